// Round 8
// baseline (148.231 us; speedup 1.0000x reference)
//
#include <hip/hip_runtime.h>
#include <float.h>

#define KNN   5
#define FEPS  1e-6f
#define NSAMP 10
#define NW    4      // waves per block
#define NT    384    // centroid tiles (padded): 384*16 = 6144

typedef _Float16 f16;
typedef __attribute__((ext_vector_type(8))) _Float16 f16x8;
typedef __attribute__((ext_vector_type(4))) float    f32x4;

static __device__ __forceinline__ unsigned umn(unsigned a, unsigned b){ return __builtin_elementwise_min(a,b); }
static __device__ __forceinline__ unsigned med3u(unsigned a, unsigned b, unsigned c){
    unsigned r; asm("v_med3_u32 %0, %1, %2, %3" : "=v"(r) : "v"(a), "v"(b), "v"(c)); return r;
}

// cent holds (cx,cy,cz,|C|^2) all pre-scaled by 1/4 — compensates the 4x
// lane-group replication of the K=5 dot product inside the MFMA.
__global__ __launch_bounds__(256) void centroid_kernel(
    const float* __restrict__ verts, const int* __restrict__ faces,
    float4* __restrict__ cent, int F, int Fpad)
{
    int i = blockIdx.x * blockDim.x + threadIdx.x;
    if (i < F) {
        int i0 = faces[3*i], i1 = faces[3*i+1], i2 = faces[3*i+2];
        float cx = (verts[3*i0+0] + verts[3*i1+0] + verts[3*i2+0]) * (1.0f/3.0f);
        float cy = (verts[3*i0+1] + verts[3*i1+1] + verts[3*i2+1]) * (1.0f/3.0f);
        float cz = (verts[3*i0+2] + verts[3*i1+2] + verts[3*i2+2]) * (1.0f/3.0f);
        float h  = fmaf(cx, cx, fmaf(cy, cy, cz*cz));
        cent[i] = make_float4(cx*0.25f, cy*0.25f, cz*0.25f, h*0.25f);
    } else if (i < Fpad) {
        cent[i] = make_float4(0.0f, 0.0f, 0.0f, 1.0e30f);  // f16-cvt -> +inf: never selected
    }
}

__global__ __launch_bounds__(256, 4) void mfma_scan(
    const float* __restrict__ verts, const int* __restrict__ faces,
    const float* __restrict__ uarr, const float* __restrict__ varr,
    const float4* __restrict__ cent,
    float* __restrict__ out, int ngroups, int N)
{
    // [wave][point-row][col-residue(pad 17)][k]: r-stride 85 mod 32 = 21 -> conflict-free merge reads
    __shared__ unsigned ml[NW][16][17][KNN];
    __shared__ float    wsum[NW];

    const int lane = threadIdx.x & 63;
    const int w    = threadIdx.x >> 6;
    const int q    = lane >> 4;
    const int m    = lane & 15;
    const int gw   = blockIdx.x * NW + w;

    float psum = 0.0f;

    if (gw < ngroups) {
        const int p  = gw * 16 + m;
        const int pc = p < N ? p : N - 1;

        // ---- point m of this group (4 lane-group duplicates, consistent) ----
        float uu = uarr[pc], vv = varr[pc];
        if (uu + vv > 1.0f) { uu = 1.0f - uu; vv = 1.0f - vv; }
        float w0 = 1.0f - uu - vv;
        int  f  = pc / NSAMP;
        int  i0 = faces[3*f], i1 = faces[3*f+1], i2 = faces[3*f+2];
        float px = verts[3*i0+0]*w0 + verts[3*i1+0]*uu + verts[3*i2+0]*vv;
        float py = verts[3*i0+1]*w0 + verts[3*i1+1]*uu + verts[3*i2+1]*vv;
        float pz = verts[3*i0+2]*w0 + verts[3*i1+2]*uu + verts[3*i2+2]*vv;
        float pp = fmaf(px, px, fmaf(py, py, pz*pz));

        // A-fragment: replicated K=5 vector [-2P, 1, |P|^2] (layout-agnostic hedge)
        f16x8 a;
        a[0] = (f16)(-2.0f*px); a[1] = (f16)(-2.0f*py); a[2] = (f16)(-2.0f*pz);
        a[3] = (f16)1.0f;       a[4] = (f16)pp;
        a[5] = (f16)0.0f;       a[6] = (f16)0.0f;       a[7] = (f16)0.0f;

        unsigned st[4][KNN];
        #pragma unroll
        for (int r = 0; r < 4; ++r)
            #pragma unroll
            for (int k = 0; k < KNN; ++k) st[r][k] = 0xFFFFFFFFu;

        const f32x4 dz = {0.0f, 0.0f, 0.0f, 0.0f};

        #pragma unroll 4
        for (int t = 0; t < NT; ++t) {
            float4 c = cent[t*16 + m];          // 16 distinct float4 per wave, L1/L2-hit
            f16x8 b;
            b[0] = (f16)c.x; b[1] = (f16)c.y; b[2] = (f16)c.z; b[3] = (f16)c.w;
            b[4] = (f16)0.25f; b[5] = (f16)0.0f; b[6] = (f16)0.0f; b[7] = (f16)0.0f;

            f32x4 d = __builtin_amdgcn_mfma_f32_16x16x32_f16(a, b, dz, 0, 0, 0);
            unsigned cidx = (unsigned)(t*16 + m);   // this lane's centroid column

            #pragma unroll
            for (int r = 0; r < 4; ++r) {
                float sv = fmaxf(d[r], 0.0f);       // clamp f16-rounding negatives
                unsigned u = (__float_as_uint(sv) & 0xFFFFE000u) | cidx;
                unsigned n4 = med3u(st[r][3], st[r][4], u);
                unsigned n3 = med3u(st[r][2], st[r][3], u);
                unsigned n2 = med3u(st[r][1], st[r][2], u);
                unsigned n1 = med3u(st[r][0], st[r][1], u);
                st[r][0] = umn(st[r][0], u);
                st[r][1] = n1; st[r][2] = n2; st[r][3] = n3; st[r][4] = n4;
            }
        }

        // lane holds rows q*4+r at col-residue m -> stash for the per-point merge
        #pragma unroll
        for (int r = 0; r < 4; ++r)
            #pragma unroll
            for (int k = 0; k < KNN; ++k)
                ml[w][q*4 + r][m][k] = st[r][k];
        // same-wave RAW through LDS: in-order per wave, no barrier needed

        // ---- merge 16 residue-lists + area test: lane = point (lanes 0..15) ----
        if (lane < 16 && gw*16 + lane < N) {
            unsigned m0=0xFFFFFFFFu,m1=0xFFFFFFFFu,m2=0xFFFFFFFFu,m3=0xFFFFFFFFu,m4=0xFFFFFFFFu;
            for (int res = 0; res < 16; ++res) {
                #pragma unroll
                for (int k = 0; k < KNN; ++k) {
                    unsigned u = ml[w][lane][res][k];
                    unsigned n4 = med3u(m3, m4, u);
                    unsigned n3 = med3u(m2, m3, u);
                    unsigned n2 = med3u(m1, m2, u);
                    unsigned n1 = med3u(m0, m1, u);
                    m0 = umn(m0, u); m1 = n1; m2 = n2; m3 = n3; m4 = n4;
                }
            }
            unsigned sel[KNN] = { m0, m1, m2, m3, m4 };
            #pragma unroll
            for (int k = 0; k < KNN; ++k) {
                int fj = (int)(sel[k] & 0x1FFFu);
                int a0 = faces[3*fj], a1 = faces[3*fj+1], a2 = faces[3*fj+2];
                float ax = verts[3*a0+0], ay = verts[3*a0+1], az = verts[3*a0+2];
                float bx = verts[3*a1+0], by = verts[3*a1+1], bz = verts[3*a1+2];
                float cx = verts[3*a2+0], cy = verts[3*a2+1], cz = verts[3*a2+2];

                float e1x = bx-ax, e1y = by-ay, e1z = bz-az;
                float e2x = cx-ax, e2y = cy-ay, e2z = cz-az;
                float nx = e1y*e2z - e1z*e2y;
                float ny = e1z*e2x - e1x*e2z;
                float nz = e1x*e2y - e1y*e2x;
                float area = 0.5f * sqrtf(nx*nx + ny*ny + nz*nz);

                float cbx = cx-bx, cby = cy-by, cbz = cz-bz;
                float pbx = px-bx, pby = py-by, pbz = pz-bz;
                float uc = (cby*pbz - cbz*pby)*nx + (cbz*pbx - cbx*pbz)*ny + (cbx*pby - cby*pbx)*nz;

                float acx = ax-cx, acy = ay-cy, acz = az-cz;
                float pcx = px-cx, pcy = py-cy, pcz = pz-cz;
                float vc = (acy*pcz - acz*pcy)*nx + (acz*pcx - acx*pcz)*ny + (acx*pcy - acy*pcx)*nz;

                float pax = px-ax, pay = py-ay, paz = pz-az;
                float wc = (e1y*paz - e1z*pay)*nx + (e1z*pax - e1x*paz)*ny + (e1x*pay - e1y*pax)*nz;

                if (fabsf(area) > FEPS && uc >= 0.0f && vc >= 0.0f && wc >= 0.0f)
                    psum += area;
            }
        }
    }

    // ---- reduce: 64-wide butterfly, across waves, one atomic/block ----
    #pragma unroll
    for (int off = 32; off > 0; off >>= 1)
        psum += __shfl_xor(psum, off, 64);
    if (lane == 0) wsum[w] = psum;
    __syncthreads();
    if (threadIdx.x == 0) {
        float t = 0.0f;
        #pragma unroll
        for (int i = 0; i < NW; ++i) t += wsum[i];
        atomicAdd(out, t);
    }
}

extern "C" void kernel_launch(void* const* d_in, const int* in_sizes, int n_in,
                              void* d_out, int out_size, void* d_ws, size_t ws_size,
                              hipStream_t stream) {
    const float* verts = (const float*)d_in[0];
    const int*   faces = (const int*)d_in[1];
    const float* u     = (const float*)d_in[2];
    const float* v     = (const float*)d_in[3];
    float*       out   = (float*)d_out;
    float4*      cent  = (float4*)d_ws;     // 6144 * 16 B = 96 KB scratch

    int F = in_sizes[1] / 3;                // 6000
    int N = in_sizes[2];                    // 60000
    int Fpad = NT * 16;                     // 6144

    hipMemsetAsync(d_out, 0, sizeof(float), stream);
    centroid_kernel<<<(Fpad + 255) / 256, 256, 0, stream>>>(verts, faces, cent, F, Fpad);

    int ngroups = (N + 15) / 16;            // 3750
    int blocks  = (ngroups + NW - 1) / NW;  // 938
    mfma_scan<<<blocks, 256, 0, stream>>>(verts, faces, u, v, cent, out, ngroups, N);
}

// Round 9
// 127.856 us; speedup vs baseline: 1.1594x; 1.1594x over previous
//
#include <hip/hip_runtime.h>
#include <float.h>

#define KNN   5
#define FEPS  1e-6f
#define NSAMP 10
#define NWAVE 8     // waves per block == centroid chunks
#define PPB   64    // points per block (lane == point)

static __device__ __forceinline__ unsigned umn(unsigned a, unsigned b){ return __builtin_elementwise_min(a, b); }
// v_med3_u32: median of 3 — single VOP3, no builtin exposed, use asm.
static __device__ __forceinline__ unsigned med3u(unsigned a, unsigned b, unsigned c){
    unsigned r; asm("v_med3_u32 %0, %1, %2, %3" : "=v"(r) : "v"(a), "v"(b), "v"(c)); return r;
}

__global__ __launch_bounds__(256) void centroid_kernel(
    const float* __restrict__ verts, const int* __restrict__ faces,
    float4* __restrict__ cent, int F, int Fpad)
{
    int i = blockIdx.x * blockDim.x + threadIdx.x;
    if (i < F) {
        int i0 = faces[3*i], i1 = faces[3*i+1], i2 = faces[3*i+2];
        float cx = (verts[3*i0+0] + verts[3*i1+0] + verts[3*i2+0]) * (1.0f/3.0f);
        float cy = (verts[3*i0+1] + verts[3*i1+1] + verts[3*i2+1]) * (1.0f/3.0f);
        float cz = (verts[3*i0+2] + verts[3*i1+2] + verts[3*i2+2]) * (1.0f/3.0f);
        float h  = fmaf(cx, cx, fmaf(cy, cy, cz*cz));   // |C|^2
        cent[i] = make_float4(cx, cy, cz, h);
    } else if (i < Fpad) {
        cent[i] = make_float4(0.0f, 0.0f, 0.0f, 3.0e38f);  // sentinel: never selected
    }
}

__global__ __launch_bounds__(512, 8) void scan_kernel(
    const float* __restrict__ verts, const int* __restrict__ faces,
    const float* __restrict__ uarr, const float* __restrict__ varr,
    const float4* __restrict__ cent,
    float* __restrict__ out, int CH, int N)
{
    __shared__ unsigned cand[KNN][NWAVE][64];   // 4B lane stride = 2-way = free
    __shared__ float wsum[NWAVE];

    const int  lane  = threadIdx.x & 63;
    const int  w     = threadIdx.x >> 6;
    const int  p     = blockIdx.x * PPB + lane;
    const bool valid = p < N;
    const int  pc    = valid ? p : N - 1;       // clamp for safe loads

    // ---- this lane's sample point P (redundant across waves, cheap) ----
    float uu = uarr[pc], vv = varr[pc];
    if (uu + vv > 1.0f) { uu = 1.0f - uu; vv = 1.0f - vv; }
    float w0 = 1.0f - uu - vv;
    int  f  = pc / NSAMP;
    int  i0 = faces[3*f], i1 = faces[3*f+1], i2 = faces[3*f+2];
    float px = verts[3*i0+0]*w0 + verts[3*i1+0]*uu + verts[3*i2+0]*vv;
    float py = verts[3*i0+1]*w0 + verts[3*i1+1]*uu + verts[3*i2+1]*vv;
    float pz = verts[3*i0+2]*w0 + verts[3*i1+2]*uu + verts[3*i2+2]*vv;
    float qx = -2.0f*px, qy = -2.0f*py, qz = -2.0f*pz;
    float pp = fmaf(px, px, fmaf(py, py, pz*pz));      // |P|^2

    // ---- wave-uniform centroid chunk of size CH (multiple of 8) ----
    const int c0 = __builtin_amdgcn_readfirstlane(CH * w);
    const float4* __restrict__ cw = cent + c0;

    // packed key: [31:13] = high float bits of d^2 (>=0, so bit order == value),
    //             [12:0]  = global centroid index -> u32 compare == lex (d2, idx)
    unsigned k0=0xFFFFFFFFu,k1=0xFFFFFFFFu,k2=0xFFFFFFFFu,k3=0xFFFFFFFFu,k4=0xFFFFFFFFu;

    #pragma unroll 8
    for (int t = 0; t < CH; ++t) {
        float4 c = cw[t];                 // wave-uniform -> s_load_dwordx4
        float h = c.w + pp;               // |C|^2 + |P|^2  (v_add: 1 SGPR ok)
        float s = fmaf(qx, c.x, fmaf(qy, c.y, fmaf(qz, c.z, h)));  // d^2 >= 0 (fp-exact enough)
        unsigned u = (__float_as_uint(s) & 0xFFFFE000u) | (unsigned)(c0 + t);
        // 5-op sorted insert via med3 (all independent)
        unsigned n4 = med3u(k3, k4, u);
        unsigned n3 = med3u(k2, k3, u);
        unsigned n2 = med3u(k1, k2, u);
        unsigned n1 = med3u(k0, k1, u);
        k0 = umn(k0, u); k1 = n1; k2 = n2; k3 = n3; k4 = n4;
    }

    cand[0][w][lane] = k0;
    cand[1][w][lane] = k1;
    cand[2][w][lane] = k2;
    cand[3][w][lane] = k3;
    cand[4][w][lane] = k4;
    __syncthreads();

    // ---- merge the 8 partial sorted top-5 lists (only waves 0..4) ----
    float psum = 0.0f;
    if (valid && w < KNN) {
        unsigned m0=0xFFFFFFFFu,m1=0xFFFFFFFFu,m2=0xFFFFFFFFu,m3=0xFFFFFFFFu,m4=0xFFFFFFFFu;
        for (int cw2 = 0; cw2 < NWAVE; ++cw2) {
            #pragma unroll
            for (int k = 0; k < KNN; ++k) {
                unsigned u = cand[k][cw2][lane];
                unsigned n4 = med3u(m3, m4, u);
                unsigned n3 = med3u(m2, m3, u);
                unsigned n2 = med3u(m1, m2, u);
                unsigned n1 = med3u(m0, m1, u);
                m0 = umn(m0, u); m1 = n1; m2 = n2; m3 = n3; m4 = n4;
            }
        }
        // wave w tests slot w's triangle for its lane's point
        unsigned mw = (w == 0) ? m0 : (w == 1) ? m1 : (w == 2) ? m2 : (w == 3) ? m3 : m4;
        int fj = (int)(mw & 0x1FFFu);

        int a0 = faces[3*fj], a1 = faces[3*fj+1], a2 = faces[3*fj+2];
        float ax = verts[3*a0+0], ay = verts[3*a0+1], az = verts[3*a0+2];
        float bx = verts[3*a1+0], by = verts[3*a1+1], bz = verts[3*a1+2];
        float cx = verts[3*a2+0], cy = verts[3*a2+1], cz = verts[3*a2+2];

        float e1x = bx-ax, e1y = by-ay, e1z = bz-az;   // b-a
        float e2x = cx-ax, e2y = cy-ay, e2z = cz-az;   // c-a
        float nx = e1y*e2z - e1z*e2y;
        float ny = e1z*e2x - e1x*e2z;
        float nz = e1x*e2y - e1y*e2x;
        float area = 0.5f * sqrtf(nx*nx + ny*ny + nz*nz);

        float cbx = cx-bx, cby = cy-by, cbz = cz-bz;
        float pbx = px-bx, pby = py-by, pbz = pz-bz;
        float uc = (cby*pbz - cbz*pby)*nx + (cbz*pbx - cbx*pbz)*ny + (cbx*pby - cby*pbx)*nz;

        float acx = ax-cx, acy = ay-cy, acz = az-cz;
        float pcx = px-cx, pcy = py-cy, pcz = pz-cz;
        float vc = (acy*pcz - acz*pcy)*nx + (acz*pcx - acx*pcz)*ny + (acx*pcy - acy*pcx)*nz;

        float pax = px-ax, pay = py-ay, paz = pz-az;
        float wc = (e1y*paz - e1z*pay)*nx + (e1z*pax - e1x*paz)*ny + (e1x*pay - e1y*pax)*nz;

        if (fabsf(area) > FEPS && uc >= 0.0f && vc >= 0.0f && wc >= 0.0f)
            psum = area;
    }

    // ---- reduce: 64-wide shuffle, across 8 waves, one atomic/block ----
    #pragma unroll
    for (int off = 32; off > 0; off >>= 1)
        psum += __shfl_down(psum, off, 64);
    if (lane == 0) wsum[w] = psum;
    __syncthreads();
    if (threadIdx.x == 0) {
        float t = 0.0f;
        #pragma unroll
        for (int i = 0; i < NWAVE; ++i) t += wsum[i];
        atomicAdd(out, t);
    }
}

extern "C" void kernel_launch(void* const* d_in, const int* in_sizes, int n_in,
                              void* d_out, int out_size, void* d_ws, size_t ws_size,
                              hipStream_t stream) {
    const float* verts = (const float*)d_in[0];
    const int*   faces = (const int*)d_in[1];
    const float* u     = (const float*)d_in[2];
    const float* v     = (const float*)d_in[3];
    float*       out   = (float*)d_out;
    float4*      cent  = (float4*)d_ws;

    int F = in_sizes[1] / 3;    // 6000
    int N = in_sizes[2];        // 60000
    int Fpad = ((F + NWAVE*8 - 1) / (NWAVE*8)) * (NWAVE*8);   // 6016 -> chunk 752 = 8*94
    int CH   = Fpad / NWAVE;

    hipMemsetAsync(d_out, 0, sizeof(float), stream);   // atomic accumulator
    centroid_kernel<<<(Fpad + 255) / 256, 256, 0, stream>>>(verts, faces, cent, F, Fpad);
    int blocks = (N + PPB - 1) / PPB;                  // 938
    scan_kernel<<<blocks, 512, 0, stream>>>(verts, faces, u, v, cent, out, CH, N);
}

// Round 10
// 103.613 us; speedup vs baseline: 1.4306x; 1.2340x over previous
//
#include <hip/hip_runtime.h>
#include <float.h>

#define KNN   5
#define FEPS  1e-6f
#define NSAMP 10
#define NWAVE 8     // waves per block == centroid chunks
#define PPB   64    // points per block (lane == point)

static __device__ __forceinline__ unsigned umn(unsigned a, unsigned b){ return __builtin_elementwise_min(a, b); }
static __device__ __forceinline__ unsigned umx(unsigned a, unsigned b){ return __builtin_elementwise_max(a, b); }
// v_med3_u32: median of 3 — single VOP3, no builtin exposed, use asm.
static __device__ __forceinline__ unsigned med3u(unsigned a, unsigned b, unsigned c){
    unsigned r; asm("v_med3_u32 %0, %1, %2, %3" : "=v"(r) : "v"(a), "v"(b), "v"(c)); return r;
}

__global__ __launch_bounds__(256) void centroid_kernel(
    const float* __restrict__ verts, const int* __restrict__ faces,
    float4* __restrict__ cent, int F, int Fpad)
{
    int i = blockIdx.x * blockDim.x + threadIdx.x;
    if (i < F) {
        int i0 = faces[3*i], i1 = faces[3*i+1], i2 = faces[3*i+2];
        float cx = (verts[3*i0+0] + verts[3*i1+0] + verts[3*i2+0]) * (1.0f/3.0f);
        float cy = (verts[3*i0+1] + verts[3*i1+1] + verts[3*i2+1]) * (1.0f/3.0f);
        float cz = (verts[3*i0+2] + verts[3*i1+2] + verts[3*i2+2]) * (1.0f/3.0f);
        float h  = fmaf(cx, cx, fmaf(cy, cy, cz*cz));   // |C|^2
        cent[i] = make_float4(cx, cy, cz, h);
    } else if (i < Fpad) {
        cent[i] = make_float4(0.0f, 0.0f, 0.0f, 3.0e38f);  // sentinel: never selected
    }
}

__global__ __launch_bounds__(512, 8) void scan_kernel(
    const float* __restrict__ verts, const int* __restrict__ faces,
    const float* __restrict__ uarr, const float* __restrict__ varr,
    const float4* __restrict__ cent,
    float* __restrict__ out, int CH, int N)
{
    __shared__ unsigned cand[KNN][NWAVE][64];   // 4B lane stride = 2-way = free
    __shared__ float wsum[NWAVE];

    const int  lane  = threadIdx.x & 63;
    const int  w     = threadIdx.x >> 6;
    const int  p     = blockIdx.x * PPB + lane;
    const bool valid = p < N;
    const int  pc    = valid ? p : N - 1;       // clamp for safe loads

    // ---- this lane's sample point P (redundant across waves, cheap) ----
    float uu = uarr[pc], vv = varr[pc];
    if (uu + vv > 1.0f) { uu = 1.0f - uu; vv = 1.0f - vv; }
    float w0 = 1.0f - uu - vv;
    int  f  = pc / NSAMP;
    int  i0 = faces[3*f], i1 = faces[3*f+1], i2 = faces[3*f+2];
    float px = verts[3*i0+0]*w0 + verts[3*i1+0]*uu + verts[3*i2+0]*vv;
    float py = verts[3*i0+1]*w0 + verts[3*i1+1]*uu + verts[3*i2+1]*vv;
    float pz = verts[3*i0+2]*w0 + verts[3*i1+2]*uu + verts[3*i2+2]*vv;
    float qx = -2.0f*px, qy = -2.0f*py, qz = -2.0f*pz;
    float pp = fmaf(px, px, fmaf(py, py, pz*pz));      // |P|^2

    // ---- wave-uniform centroid chunk of size CH (multiple of 8) ----
    const int c0 = __builtin_amdgcn_readfirstlane(CH * w);
    const float4* __restrict__ cw = cent + c0;

    // keep the key-pack mask in a VGPR so v_bfi_b32 can take the SGPR index
    unsigned maskv;
    asm("v_mov_b32 %0, 0xFFFFE000" : "=v"(maskv));

    // packed key: [31:13] = high float bits of d^2 (>=0, so bit order == value),
    //             [12:0]  = global centroid index -> u32 compare == lex (d2, idx)
    unsigned k0=0xFFFFFFFFu,k1=0xFFFFFFFFu,k2=0xFFFFFFFFu,k3=0xFFFFFFFFu,k4=0xFFFFFFFFu;

    #pragma unroll 4
    for (int t = 0; t < CH; t += 2) {
        float4 ca = cw[t];                // wave-uniform -> s_load
        float4 cb = cw[t+1];
        float ha = ca.w + pp;             // |C|^2 + |P|^2
        float hb = cb.w + pp;
        float sa = fmaf(qx, ca.x, fmaf(qy, ca.y, fmaf(qz, ca.z, ha)));  // d^2 >= 0
        float sb = fmaf(qx, cb.x, fmaf(qy, cb.y, fmaf(qz, cb.z, hb)));
        unsigned ua, ub;
        asm("v_bfi_b32 %0, %1, %2, %3" : "=v"(ua)
            : "v"(maskv), "v"(__float_as_uint(sa)), "s"(c0 + t));
        asm("v_bfi_b32 %0, %1, %2, %3" : "=v"(ub)
            : "v"(maskv), "v"(__float_as_uint(sb)), "s"(c0 + t + 1));
        unsigned wm = umn(ua, ub);
        unsigned lm = umx(ua, ub);
        // insert the pair-min (5 ops)
        {
            unsigned n4 = med3u(k3, k4, wm);
            unsigned n3 = med3u(k2, k3, wm);
            unsigned n2 = med3u(k1, k2, wm);
            unsigned n1 = med3u(k0, k1, wm);
            k0 = umn(k0, wm); k1 = n1; k2 = n2; k3 = n3; k4 = n4;
        }
        // pair-max only matters if it would displace k4 for some lane.
        // Inserting an oversized key is an identity on the sorted list, so
        // no lane masking is needed -> exact same result as sequential.
        if (__any(lm < k4)) {
            unsigned n4 = med3u(k3, k4, lm);
            unsigned n3 = med3u(k2, k3, lm);
            unsigned n2 = med3u(k1, k2, lm);
            unsigned n1 = med3u(k0, k1, lm);
            k0 = umn(k0, lm); k1 = n1; k2 = n2; k3 = n3; k4 = n4;
        }
    }

    cand[0][w][lane] = k0;
    cand[1][w][lane] = k1;
    cand[2][w][lane] = k2;
    cand[3][w][lane] = k3;
    cand[4][w][lane] = k4;
    __syncthreads();

    // ---- merge the 8 partial sorted top-5 lists (only waves 0..4) ----
    float psum = 0.0f;
    if (valid && w < KNN) {
        unsigned m0=0xFFFFFFFFu,m1=0xFFFFFFFFu,m2=0xFFFFFFFFu,m3=0xFFFFFFFFu,m4=0xFFFFFFFFu;
        for (int cw2 = 0; cw2 < NWAVE; ++cw2) {
            #pragma unroll
            for (int k = 0; k < KNN; ++k) {
                unsigned u = cand[k][cw2][lane];
                unsigned n4 = med3u(m3, m4, u);
                unsigned n3 = med3u(m2, m3, u);
                unsigned n2 = med3u(m1, m2, u);
                unsigned n1 = med3u(m0, m1, u);
                m0 = umn(m0, u); m1 = n1; m2 = n2; m3 = n3; m4 = n4;
            }
        }
        // wave w tests slot w's triangle for its lane's point
        unsigned mw = (w == 0) ? m0 : (w == 1) ? m1 : (w == 2) ? m2 : (w == 3) ? m3 : m4;
        int fj = (int)(mw & 0x1FFFu);

        int a0 = faces[3*fj], a1 = faces[3*fj+1], a2 = faces[3*fj+2];
        float ax = verts[3*a0+0], ay = verts[3*a0+1], az = verts[3*a0+2];
        float bx = verts[3*a1+0], by = verts[3*a1+1], bz = verts[3*a1+2];
        float cx = verts[3*a2+0], cy = verts[3*a2+1], cz = verts[3*a2+2];

        float e1x = bx-ax, e1y = by-ay, e1z = bz-az;   // b-a
        float e2x = cx-ax, e2y = cy-ay, e2z = cz-az;   // c-a
        float nx = e1y*e2z - e1z*e2y;
        float ny = e1z*e2x - e1x*e2z;
        float nz = e1x*e2y - e1y*e2x;
        float area = 0.5f * sqrtf(nx*nx + ny*ny + nz*nz);

        float cbx = cx-bx, cby = cy-by, cbz = cz-bz;
        float pbx = px-bx, pby = py-by, pbz = pz-bz;
        float uc = (cby*pbz - cbz*pby)*nx + (cbz*pbx - cbx*pbz)*ny + (cbx*pby - cby*pbx)*nz;

        float acx = ax-cx, acy = ay-cy, acz = az-cz;
        float pcx = px-cx, pcy = py-cy, pcz = pz-cz;
        float vc = (acy*pcz - acz*pcy)*nx + (acz*pcx - acx*pcz)*ny + (acx*pcy - acy*pcx)*nz;

        float pax = px-ax, pay = py-ay, paz = pz-az;
        float wc = (e1y*paz - e1z*pay)*nx + (e1z*pax - e1x*paz)*ny + (e1x*pay - e1y*pax)*nz;

        if (fabsf(area) > FEPS && uc >= 0.0f && vc >= 0.0f && wc >= 0.0f)
            psum = area;
    }

    // ---- reduce: 64-wide shuffle, across 8 waves, one atomic/block ----
    #pragma unroll
    for (int off = 32; off > 0; off >>= 1)
        psum += __shfl_down(psum, off, 64);
    if (lane == 0) wsum[w] = psum;
    __syncthreads();
    if (threadIdx.x == 0) {
        float t = 0.0f;
        #pragma unroll
        for (int i = 0; i < NWAVE; ++i) t += wsum[i];
        atomicAdd(out, t);
    }
}

extern "C" void kernel_launch(void* const* d_in, const int* in_sizes, int n_in,
                              void* d_out, int out_size, void* d_ws, size_t ws_size,
                              hipStream_t stream) {
    const float* verts = (const float*)d_in[0];
    const int*   faces = (const int*)d_in[1];
    const float* u     = (const float*)d_in[2];
    const float* v     = (const float*)d_in[3];
    float*       out   = (float*)d_out;
    float4*      cent  = (float4*)d_ws;

    int F = in_sizes[1] / 3;    // 6000
    int N = in_sizes[2];        // 60000
    int Fpad = ((F + NWAVE*8 - 1) / (NWAVE*8)) * (NWAVE*8);   // 6016 -> chunk 752 = 8*94
    int CH   = Fpad / NWAVE;

    hipMemsetAsync(d_out, 0, sizeof(float), stream);   // atomic accumulator
    centroid_kernel<<<(Fpad + 255) / 256, 256, 0, stream>>>(verts, faces, cent, F, Fpad);
    int blocks = (N + PPB - 1) / PPB;                  // 938
    scan_kernel<<<blocks, 512, 0, stream>>>(verts, faces, u, v, cent, out, CH, N);
}